// Round 11
// baseline (2087.981 us; speedup 1.0000x reference)
//
#include <hip/hip_runtime.h>
#include <math.h>

#define NPTS 50000
#define NG   128
#define DD   32
#define FF   64
#define AA   8
#define HINC 1120   // DD + FF + 2*FF*AA
#define EPSV 1e-5f
#define CH   64
#define SLOTS 10    // chunk slots per graph (last slot loops for overflow)

__device__ __forceinline__ float tanh_fast(float x) {
    float e = __expf(-2.f * fabsf(x));
    float r = __fdividef(1.f - e, 1.f + e);
    return copysignf(r, x);
}

// ---------------------------------------------------------------- setup: offs + stats zero + counters + Weff/beff fold
__global__ __launch_bounds__(256) void k_setup(const int* __restrict__ batch,
                                               const float* __restrict__ W_in,
                                               const float* __restrict__ b_in,
                                               const float* __restrict__ W_out,
                                               const float* __restrict__ b_out,
                                               int* __restrict__ offs,
                                               float* __restrict__ stats,
                                               unsigned int* __restrict__ gcnt,
                                               float* __restrict__ Weff,
                                               float* __restrict__ beff) {
    int t = threadIdx.x, bid = blockIdx.x;
    if (bid == 0) {
        if (t <= NG) {
            int lo = 0, hi = NPTS;
            while (lo < hi) { int mid = (lo+hi)>>1; if (batch[mid] < t) lo = mid+1; else hi = mid; }
            offs[t] = lo;
        }
        if (t < 32) stats[t] = 0.f;
        for (int k = t; k < 9*NG; k += 256) gcnt[k] = 0u;   // ALL layer x graph counters
    } else {
        int j = bid - 1;
        const float* W0 = W_out + (size_t)j*HINC*DD;   // rows 0..31
        const float* W1 = W0 + DD*DD;                  // rows 32..95
        const float* Wi = W_in + (size_t)j*DD*FF;
        for (int e = t; e < DD*DD; e += 256) {
            int i = e >> 5, d = e & 31;
            float s = W0[e];
            for (int f = 0; f < FF; f++) s += Wi[i*FF+f] * W1[f*DD+d];
            Weff[j*DD*DD + e] = s;
        }
        if (t < DD) {
            float s = b_out[j*DD + t];
            for (int f = 0; f < FF; f++) s += b_in[j*FF+f] * W1[f*DD+t];
            beff[j*DD + t] = s;
        }
    }
}

// ---------------------------------------------------------------- kA: (embed|gln) -> xp -> attn -> slot partials; LAST slot-block per graph folds B
__global__ __launch_bounds__(512) void k_A(const float* __restrict__ x,
                                           const float* __restrict__ Wi,
                                           const float* __restrict__ bi,
                                           const float* __restrict__ lniw,
                                           const float* __restrict__ lnib,
                                           const float* __restrict__ inb,
                                           const float* __restrict__ stats,
                                           const float* __restrict__ gw,
                                           const float* __restrict__ gb,
                                           const float* __restrict__ Win,
                                           const float* __restrict__ bin,
                                           const float* __restrict__ Wsc,
                                           const float* __restrict__ bsc,
                                           const int* __restrict__ offs,
                                           float* __restrict__ psum,
                                           float* __restrict__ pmax,
                                           float* __restrict__ hout,
                                           const float* __restrict__ Wagg,  // W_out[j] + 96*DD
                                           const float* __restrict__ beff,
                                           float* __restrict__ aggW,
                                           unsigned int* __restrict__ gcnt, // per-layer base: NG counters
                                           int isL0) {
    int g = blockIdx.x / SLOTS;
    int s = blockIdx.x - g*SLOTS;
    int gs = offs[g], cnt = offs[g+1] - gs;
    int start = s*CH;
    const bool active = (start < cnt);
    int end = (s == SLOTS-1) ? cnt : min(cnt, start + CH);

    __shared__ float hs[CH][36];
    __shared__ float sxp[CH][68];             // padded: conflict-free
    __shared__ float sattn[CH][9];
    __shared__ float sWin[DD*FF];
    __shared__ float sScT[AA*FF];             // Wsc transposed [a][f]
    __shared__ unsigned sOld;

    const int t = threadIdx.x;

    if (active) {
        ((float4*)sWin)[t] = ((const float4*)Win)[t];              // 512 float4 == 2048 floats
        { int a = t >> 6, f = t & 63; sScT[t] = Wsc[f*AA + a]; }   // 512 == AA*FF

        float gm = 0.f, ginv = 1.f;
        if (stats) {
            const float invM = 1.f/((float)NPTS*DD);
            gm = stats[0]*invM;
            float var = stats[1]*invM - gm*gm;
            ginv = 1.f/(sqrtf(fmaxf(var, 0.f)) + EPSV);
        }

        const int pt = t >> 3, q = t & 7;
        const int fo = q * 8;
        const int ca = t >> 6, cf = t & 63;
        const float bscv = bsc[q];
        const float4 bi0 = *(const float4*)&bin[fo];
        const float4 bi1 = *(const float4*)&bin[fo+4];
        float csum = 0.f, cmax = -INFINITY;

        for (int base = gs + start; base < gs + end; base += CH) {
            int np = min(CH, gs + end - base);
            __syncthreads();                  // weights staged (iter 0) / LDS consumed (iter >0)
            // ---- phase 1: stage point rows into hs (embed for L0, gln-load otherwise)
            {
                int pp = t >> 3, d4 = (t & 7)*4;
                if (pp < np) {
                    int n = base + pp;
                    if (isL0) {
                        float x0 = x[n*3], x1 = x[n*3+1], x2 = x[n*3+2];
                        float tv0 = x0*Wi[d4+0] + x1*Wi[DD+d4+0] + x2*Wi[2*DD+d4+0] + bi[d4+0];
                        float tv1 = x0*Wi[d4+1] + x1*Wi[DD+d4+1] + x2*Wi[2*DD+d4+1] + bi[d4+1];
                        float tv2 = x0*Wi[d4+2] + x1*Wi[DD+d4+2] + x2*Wi[2*DD+d4+2] + bi[d4+2];
                        float tv3 = x0*Wi[d4+3] + x1*Wi[DD+d4+3] + x2*Wi[2*DD+d4+3] + bi[d4+3];
                        float sm = (tv0+tv1) + (tv2+tv3);
                        sm += __shfl_xor(sm, 1); sm += __shfl_xor(sm, 2); sm += __shfl_xor(sm, 4);
                        float mm = sm * (1.f/DD);
                        float c0 = tv0-mm, c1 = tv1-mm, c2 = tv2-mm, c3 = tv3-mm;
                        float qq = (c0*c0 + c1*c1) + (c2*c2 + c3*c3);
                        qq += __shfl_xor(qq, 1); qq += __shfl_xor(qq, 2); qq += __shfl_xor(qq, 4);
                        float inv = 1.f/sqrtf(qq*(1.f/DD) + EPSV);
                        float o0 = tanh_fast(c0*inv*lniw[d4+0] + lnib[d4+0]);
                        float o1 = tanh_fast(c1*inv*lniw[d4+1] + lnib[d4+1]);
                        float o2 = tanh_fast(c2*inv*lniw[d4+2] + lnib[d4+2]);
                        float o3 = tanh_fast(c3*inv*lniw[d4+3] + lnib[d4+3]);
                        hs[pp][d4+0] = o0; hs[pp][d4+1] = o1; hs[pp][d4+2] = o2; hs[pp][d4+3] = o3;
                        *(float4*)&hout[(size_t)n*DD + d4] = make_float4(o0,o1,o2,o3);
                    } else {
                        float4 v = *(const float4*)&inb[(size_t)n*DD + d4];
                        float4 w4 = make_float4(1,1,1,1), b4 = make_float4(0,0,0,0);
                        if (gw) { w4 = *(const float4*)&gw[d4]; b4 = *(const float4*)&gb[d4]; }
                        hs[pp][d4+0] = (v.x-gm)*ginv*w4.x + b4.x;
                        hs[pp][d4+1] = (v.y-gm)*ginv*w4.y + b4.y;
                        hs[pp][d4+2] = (v.z-gm)*ginv*w4.z + b4.z;
                        hs[pp][d4+3] = (v.w-gm)*ginv*w4.w + b4.w;
                    }
                }
            }
            __syncthreads();
            // ---- phase 2: xp + attn (8 threads per point)
            if (pt < np) {
                float xr[8] = {bi0.x,bi0.y,bi0.z,bi0.w,bi1.x,bi1.y,bi1.z,bi1.w};
                #pragma unroll
                for (int k = 0; k < DD; k++) {
                    float hv = hs[pt][k];
                    float4 wa = *(const float4*)&sWin[k*FF + fo];
                    float4 wb = *(const float4*)&sWin[k*FF + fo + 4];
                    xr[0] += hv*wa.x; xr[1] += hv*wa.y; xr[2] += hv*wa.z; xr[3] += hv*wa.w;
                    xr[4] += hv*wb.x; xr[5] += hv*wb.y; xr[6] += hv*wb.z; xr[7] += hv*wb.w;
                }
                float pa[8];
                #pragma unroll
                for (int a = 0; a < 8; a++) {
                    float4 wa = *(const float4*)&sScT[a*FF + fo];
                    float4 wb = *(const float4*)&sScT[a*FF + fo + 4];
                    pa[a] = xr[0]*wa.x + xr[1]*wa.y + xr[2]*wa.z + xr[3]*wa.w
                          + xr[4]*wb.x + xr[5]*wb.y + xr[6]*wb.z + xr[7]*wb.w;
                }
                #pragma unroll
                for (int msk = 1; msk < 8; msk <<= 1) {
                    #pragma unroll
                    for (int a = 0; a < 8; a++) pa[a] += __shfl_xor(pa[a], msk);
                }
                sattn[pt][q] = __expf(-fabsf(pa[q] + bscv));
                *(float4*)&sxp[pt][fo]   = make_float4(xr[0],xr[1],xr[2],xr[3]);
                *(float4*)&sxp[pt][fo+4] = make_float4(xr[4],xr[5],xr[6],xr[7]);
            }
            __syncthreads();
            // ---- phase 3: accumulate one (a,f) cell per thread
            for (int pp = 0; pp < np; pp++) {
                float w = sattn[pp][ca] * sxp[pp][cf];
                csum += w; cmax = fmaxf(cmax, w);
            }
        }
        size_t pb = ((size_t)g*SLOTS + s)*512;
        // device-scope stores so the B-performing block (any XCD) sees them
        __hip_atomic_store(&psum[pb + t], csum, __ATOMIC_RELAXED, __HIP_MEMORY_SCOPE_AGENT);
        __hip_atomic_store(&pmax[pb + t], cmax, __ATOMIC_RELAXED, __HIP_MEMORY_SCOPE_AGENT);
        __threadfence();                       // release by the STORING thread
    }

    // ---- last-block-per-graph protocol: fold k_B here ----
    __syncthreads();
    if (t == 0) sOld = atomicAdd(&gcnt[g], 1u);
    __syncthreads();
    if (sOld == SLOTS - 1) {                   // this block is last for graph g (uniform)
        __threadfence();                       // acquire: see all slots' partials
        float* aggb = &hs[0][0];               // 1024 floats (alias, hs is dead)
        float (*redb)[DD] = (float(*)[DD])(&sxp[0][0]);  // 512 floats (alias)
        int nch = min((cnt + CH - 1)/CH, SLOTS);
        float sum = 0.f, mx = -INFINITY;
        size_t pb2 = (size_t)g*SLOTS*512;
        for (int s2 = 0; s2 < nch; s2++) {
            sum += __hip_atomic_load(&psum[pb2 + s2*512 + t], __ATOMIC_RELAXED, __HIP_MEMORY_SCOPE_AGENT);
            mx = fmaxf(mx, __hip_atomic_load(&pmax[pb2 + s2*512 + t], __ATOMIC_RELAXED, __HIP_MEMORY_SCOPE_AGENT));
        }
        float mean = sum / fmaxf((float)cnt, 1.f);
        if (cnt <= 0) { mean = 0.f; mx = 0.f; }
        int a = t >> 6, f = t & 63;
        aggb[a*2*FF + f]      = mean;
        aggb[a*2*FF + FF + f] = mx;
        __syncthreads();
        int d = t & 31, grp = t >> 5;          // 16 groups x 64 k
        float acc = 0.f;
        #pragma unroll
        for (int k2 = 0; k2 < 64; k2++) {
            int k = grp*64 + k2;
            acc += aggb[k] * Wagg[k*DD + d];
        }
        redb[grp][d] = acc;
        __syncthreads();
        if (t < DD) {
            float r = 0.f;
            #pragma unroll
            for (int qq = 0; qq < 16; qq++) r += redb[qq][t];
            aggW[g*DD + t] = r + beff[t];
        }
    }
}

// ---------------------------------------------------------------- kC: out = tanh(gln(in)@Weff + aggW[g]); global stats (r3-proven)
__global__ __launch_bounds__(512) void k_C(const float* __restrict__ inb,
                                           const float* __restrict__ stats,
                                           const float* __restrict__ gw,
                                           const float* __restrict__ gb,
                                           const float* __restrict__ aggW,
                                           const int* __restrict__ batch,
                                           const float* __restrict__ Weff,
                                           float* __restrict__ tbuf,
                                           float* __restrict__ statsO) {
    __shared__ float hs[64][36];
    __shared__ float sW[DD][36];
    int t = threadIdx.x;
    for (int k = t; k < DD*DD; k += 512) sW[k >> 5][k & 31] = Weff[k];

    float m = 0.f, inv = 1.f;
    if (stats) {
        const float invM = 1.f/((float)NPTS*DD);
        m = stats[0]*invM;
        float var = stats[1]*invM - m*m;
        inv = 1.f/(sqrtf(fmaxf(var, 0.f)) + EPSV);
    }
    int b0 = blockIdx.x * 64;
    // phase 1: load + gln
    {
        int pp = t >> 3, d4 = (t & 7)*4;
        int n = b0 + pp;
        if (n < NPTS) {
            float4 v = *(const float4*)&inb[(size_t)n*DD + d4];
            float4 w4 = make_float4(1,1,1,1), b4 = make_float4(0,0,0,0);
            if (gw) { w4 = *(const float4*)&gw[d4]; b4 = *(const float4*)&gb[d4]; }
            hs[pp][d4+0] = (v.x-m)*inv*w4.x + b4.x;
            hs[pp][d4+1] = (v.y-m)*inv*w4.y + b4.y;
            hs[pp][d4+2] = (v.z-m)*inv*w4.z + b4.z;
            hs[pp][d4+3] = (v.w-m)*inv*w4.w + b4.w;
        }
    }
    __syncthreads();
    int pt = t >> 3, q4 = (t & 7)*4;
    int n = b0 + pt;
    float s1 = 0.f, s2 = 0.f;
    if (n < NPTS) {
        int g = batch[n];
        float4 a0 = *(const float4*)&aggW[g*DD + q4];
        float acc0 = a0.x, acc1 = a0.y, acc2 = a0.z, acc3 = a0.w;
        #pragma unroll
        for (int k = 0; k < DD; k++) {
            float hv = hs[pt][k];
            float4 w = *(const float4*)&sW[k][q4];
            acc0 += hv*w.x; acc1 += hv*w.y; acc2 += hv*w.z; acc3 += hv*w.w;
        }
        float4 o;
        o.x = tanh_fast(acc0); o.y = tanh_fast(acc1);
        o.z = tanh_fast(acc2); o.w = tanh_fast(acc3);
        *(float4*)&tbuf[(size_t)n*DD + q4] = o;
        s1 = (o.x + o.y) + (o.z + o.w);
        s2 = (o.x*o.x + o.y*o.y) + (o.z*o.z + o.w*o.w);
    }
    #pragma unroll
    for (int o = 32; o > 0; o >>= 1) { s1 += __shfl_down(s1, o); s2 += __shfl_down(s2, o); }
    __shared__ float rs1[8], rs2[8];
    int wid = t >> 6;
    if ((t & 63) == 0) { rs1[wid] = s1; rs2[wid] = s2; }
    __syncthreads();
    if (t == 0) {
        float a1 = 0.f, a2 = 0.f;
        #pragma unroll
        for (int qq = 0; qq < 8; qq++) { a1 += rs1[qq]; a2 += rs2[qq]; }
        atomicAdd(&statsO[0], a1);
        atomicAdd(&statsO[1], a2);
    }
}

// ---------------------------------------------------------------- readout: segment mean of gln(tbuf) -> 3x (dense+ln+tanh) -> dot
__global__ __launch_bounds__(256) void k_read(const float* __restrict__ tbuf,
                                              const float* __restrict__ stats,
                                              const float* __restrict__ gw,
                                              const float* __restrict__ gb,
                                              const int* __restrict__ offs,
                                              const float* __restrict__ Wp,
                                              const float* __restrict__ bp,
                                              const float* __restrict__ lnw,
                                              const float* __restrict__ lnb,
                                              const float* __restrict__ Wpo,
                                              const float* __restrict__ bpo,
                                              float* __restrict__ out) {
    int g = blockIdx.x;
    int t = threadIdx.x;
    int d = t & 31, pl = t >> 5;   // 8 point-lanes x 32 dims
    int s0 = offs[g], e0 = offs[g+1];
    float acc = 0.f;
    for (int n = s0 + pl; n < e0; n += 8) acc += tbuf[(size_t)n*DD + d];
    __shared__ float red[8][DD];
    red[pl][d] = acc;
    __syncthreads();
    __shared__ float sv[DD];
    if (t < DD) {
        float r = 0.f;
        #pragma unroll
        for (int qq = 0; qq < 8; qq++) r += red[qq][t];
        const float invM = 1.f/((float)NPTS*DD);
        float m = stats[0]*invM;
        float var = stats[1]*invM - m*m;
        float inv = 1.f/(sqrtf(fmaxf(var, 0.f)) + EPSV);
        float cnt = (float)(e0 - s0);
        float mean = r / fmaxf(cnt, 1.f);
        sv[t] = (e0 > s0) ? (mean - m)*inv*gw[t] + gb[t] : 0.f;
    }
    __syncthreads();
    for (int j = 0; j < 3; j++) {
        float yv = 0.f;
        if (t < DD) {
            float y = bp[j*DD + t];
            #pragma unroll
            for (int i = 0; i < DD; i++) y += sv[i] * Wp[j*DD*DD + i*DD + t];
            float sum = y;
            #pragma unroll
            for (int o = 1; o < 32; o <<= 1) sum += __shfl_xor(sum, o);
            float m = sum * (1.f/DD);
            float c = y - m;
            float sq = c*c;
            #pragma unroll
            for (int o = 1; o < 32; o <<= 1) sq += __shfl_xor(sq, o);
            float var = sq * (1.f/DD);
            yv = tanh_fast(c / sqrtf(var + EPSV) * lnw[j*DD+t] + lnb[j*DD+t]);
        }
        __syncthreads();
        if (t < DD) sv[t] = yv;
        __syncthreads();
    }
    if (t < DD) {
        float p = sv[t] * Wpo[t];
        #pragma unroll
        for (int o = 1; o < 32; o <<= 1) p += __shfl_xor(p, o);
        if (t == 0) out[g] = p + bpo[0];
    }
}

extern "C" void kernel_launch(void* const* d_in, const int* in_sizes, int n_in,
                              void* d_out, int out_size, void* d_ws, size_t ws_size,
                              hipStream_t stream) {
    const float* x     = (const float*)d_in[0];
    const int*   batch = (const int*)  d_in[1];
    const float* Wi    = (const float*)d_in[2];
    const float* bi    = (const float*)d_in[3];
    const float* lni_w = (const float*)d_in[4];
    const float* lni_b = (const float*)d_in[5];
    const float* W_in  = (const float*)d_in[6];
    const float* b_in  = (const float*)d_in[7];
    const float* W_sc  = (const float*)d_in[8];
    const float* b_sc  = (const float*)d_in[9];
    const float* W_out = (const float*)d_in[10];
    const float* b_out = (const float*)d_in[11];
    const float* gln_w = (const float*)d_in[12];
    const float* gln_b = (const float*)d_in[13];
    const float* Wp    = (const float*)d_in[14];
    const float* bp    = (const float*)d_in[15];
    const float* lnp_w = (const float*)d_in[16];
    const float* lnp_b = (const float*)d_in[17];
    const float* Wpo   = (const float*)d_in[18];
    const float* bpo   = (const float*)d_in[19];
    float* out = (float*)d_out;

    float* ws    = (float*)d_ws;
    float* h     = ws;                                  // NPTS*32
    float* tbuf  = h + (size_t)NPTS*DD;                 // NPTS*32
    float* aggW  = tbuf + (size_t)NPTS*DD;              // NG*32
    float* stats = aggW + NG*DD;                        // 32
    float* Weff  = stats + 32;                          // 3*1024
    float* beff  = Weff + 3*DD*DD;                      // 96
    float* psum  = beff + 3*DD;                         // NG*SLOTS*512
    float* pmax  = psum + (size_t)NG*SLOTS*512;         // NG*SLOTS*512
    int*   offs  = (int*)(pmax + (size_t)NG*SLOTS*512); // NG+1
    unsigned int* gcnt = (unsigned int*)(offs + NG + 1);// 9*NG (one per layer x graph)

    k_setup<<<4, 256, 0, stream>>>(batch, W_in, b_in, W_out, b_out, offs, stats, gcnt, Weff, beff);

    for (int L = 0; L < 9; ++L) {
        int j = L % 3;
        int pj = (L + 2) % 3;
        const float* inb = L ? tbuf : h;
        const float* st  = L ? stats + 2*(L-1) : nullptr;
        const float* pgw = L ? gln_w + pj*DD : nullptr;
        const float* pgb = L ? gln_b + pj*DD : nullptr;
        k_A<<<NG*SLOTS, 512, 0, stream>>>(
            x, Wi, bi, lni_w, lni_b,
            inb, st, pgw, pgb,
            W_in + (size_t)j*DD*FF, b_in + j*FF,
            W_sc + (size_t)j*FF*AA, b_sc + j*AA,
            offs, psum, pmax, h,
            W_out + (size_t)j*HINC*DD + (size_t)96*DD, beff + j*DD,
            aggW, gcnt + (size_t)L*NG, (L == 0) ? 1 : 0);
        k_C<<<(NPTS+CH-1)/CH, 512, 0, stream>>>(
            inb, st, pgw, pgb, aggW, batch,
            Weff + (size_t)j*DD*DD, tbuf, stats + 2*L);
    }
    k_read<<<NG, 256, 0, stream>>>(tbuf, stats + 16, gln_w + 2*DD, gln_b + 2*DD,
                                   offs, Wp, bp, lnp_w, lnp_b, Wpo, bpo, out);
}

// Round 12
// 486.002 us; speedup vs baseline: 4.2962x; 4.2962x over previous
//
#include <hip/hip_runtime.h>
#include <math.h>

#define NPTS 50000
#define NG   128
#define DD   32
#define FF   64
#define AA   8
#define HINC 1120   // DD + FF + 2*FF*AA
#define EPSV 1e-5f
#define CH   64
#define SLOTS 10    // chunk slots per graph (last slot loops for overflow)

__device__ __forceinline__ float tanh_fast(float x) {
    float e = __expf(-2.f * fabsf(x));
    float r = __fdividef(1.f - e, 1.f + e);
    return copysignf(r, x);
}

// ---------------------------------------------------------------- setup: offs + stats zero + Weff/beff fold
__global__ __launch_bounds__(256) void k_setup(const int* __restrict__ batch,
                                               const float* __restrict__ W_in,
                                               const float* __restrict__ b_in,
                                               const float* __restrict__ W_out,
                                               const float* __restrict__ b_out,
                                               int* __restrict__ offs,
                                               float* __restrict__ stats,
                                               float* __restrict__ Weff,
                                               float* __restrict__ beff) {
    int t = threadIdx.x, bid = blockIdx.x;
    if (bid == 0) {
        if (t <= NG) {
            int lo = 0, hi = NPTS;
            while (lo < hi) { int mid = (lo+hi)>>1; if (batch[mid] < t) lo = mid+1; else hi = mid; }
            offs[t] = lo;
        }
        if (t < 32) stats[t] = 0.f;
    } else {
        int j = bid - 1;
        const float* W0 = W_out + (size_t)j*HINC*DD;   // rows 0..31
        const float* W1 = W0 + DD*DD;                  // rows 32..95
        const float* Wi = W_in + (size_t)j*DD*FF;
        for (int e = t; e < DD*DD; e += 256) {
            int i = e >> 5, d = e & 31;
            float s = W0[e];
            for (int f = 0; f < FF; f++) s += Wi[i*FF+f] * W1[f*DD+d];
            Weff[j*DD*DD + e] = s;
        }
        if (t < DD) {
            float s = b_out[j*DD + t];
            for (int f = 0; f < FF; f++) s += b_in[j*FF+f] * W1[f*DD+t];
            beff[j*DD + t] = s;
        }
    }
}

// ---------------------------------------------------------------- kA: (embed|gln) -> xp -> attn -> slot partials (r9-proven)
// inactive slot-blocks zero-fill their partials so k_C can read all SLOTS unconditionally
__global__ __launch_bounds__(512) void k_A(const float* __restrict__ x,
                                           const float* __restrict__ Wi,
                                           const float* __restrict__ bi,
                                           const float* __restrict__ lniw,
                                           const float* __restrict__ lnib,
                                           const float* __restrict__ inb,
                                           const float* __restrict__ stats,
                                           const float* __restrict__ gw,
                                           const float* __restrict__ gb,
                                           const float* __restrict__ Win,
                                           const float* __restrict__ bin,
                                           const float* __restrict__ Wsc,
                                           const float* __restrict__ bsc,
                                           const int* __restrict__ offs,
                                           float* __restrict__ psum,
                                           float* __restrict__ pmax,
                                           float* __restrict__ hout,
                                           int isL0) {
    int g = blockIdx.x / SLOTS;
    int s = blockIdx.x - g*SLOTS;
    int gs = offs[g], cnt = offs[g+1] - gs;
    int start = s*CH;
    const int t = threadIdx.x;
    size_t pb = ((size_t)g*SLOTS + s)*512;
    if (start >= cnt) {                       // inactive: publish identity partials
        psum[pb + t] = 0.f;
        pmax[pb + t] = -INFINITY;
        return;
    }
    int end = (s == SLOTS-1) ? cnt : min(cnt, start + CH);

    __shared__ float hs[CH][36];
    __shared__ float sxp[CH][68];             // padded: conflict-free
    __shared__ float sattn[CH][9];
    __shared__ float sWin[DD*FF];
    __shared__ float sScT[AA*FF];             // Wsc transposed [a][f]

    ((float4*)sWin)[t] = ((const float4*)Win)[t];              // 512 float4 == 2048 floats
    { int a = t >> 6, f = t & 63; sScT[t] = Wsc[f*AA + a]; }   // 512 == AA*FF

    float gm = 0.f, ginv = 1.f;
    if (stats) {
        const float invM = 1.f/((float)NPTS*DD);
        gm = stats[0]*invM;
        float var = stats[1]*invM - gm*gm;
        ginv = 1.f/(sqrtf(fmaxf(var, 0.f)) + EPSV);
    }

    const int pt = t >> 3, q = t & 7;
    const int fo = q * 8;
    const int ca = t >> 6, cf = t & 63;
    const float bscv = bsc[q];
    const float4 bi0 = *(const float4*)&bin[fo];
    const float4 bi1 = *(const float4*)&bin[fo+4];
    float csum = 0.f, cmax = -INFINITY;

    for (int base = gs + start; base < gs + end; base += CH) {
        int np = min(CH, gs + end - base);
        __syncthreads();                      // weights staged (iter 0) / LDS consumed (iter >0)
        // ---- phase 1: stage point rows into hs (embed for L0, gln-load otherwise)
        {
            int pp = t >> 3, d4 = (t & 7)*4;
            if (pp < np) {
                int n = base + pp;
                if (isL0) {
                    float x0 = x[n*3], x1 = x[n*3+1], x2 = x[n*3+2];
                    float tv0 = x0*Wi[d4+0] + x1*Wi[DD+d4+0] + x2*Wi[2*DD+d4+0] + bi[d4+0];
                    float tv1 = x0*Wi[d4+1] + x1*Wi[DD+d4+1] + x2*Wi[2*DD+d4+1] + bi[d4+1];
                    float tv2 = x0*Wi[d4+2] + x1*Wi[DD+d4+2] + x2*Wi[2*DD+d4+2] + bi[d4+2];
                    float tv3 = x0*Wi[d4+3] + x1*Wi[DD+d4+3] + x2*Wi[2*DD+d4+3] + bi[d4+3];
                    float sm = (tv0+tv1) + (tv2+tv3);
                    sm += __shfl_xor(sm, 1); sm += __shfl_xor(sm, 2); sm += __shfl_xor(sm, 4);
                    float mm = sm * (1.f/DD);
                    float c0 = tv0-mm, c1 = tv1-mm, c2 = tv2-mm, c3 = tv3-mm;
                    float qq = (c0*c0 + c1*c1) + (c2*c2 + c3*c3);
                    qq += __shfl_xor(qq, 1); qq += __shfl_xor(qq, 2); qq += __shfl_xor(qq, 4);
                    float inv = 1.f/sqrtf(qq*(1.f/DD) + EPSV);
                    float o0 = tanh_fast(c0*inv*lniw[d4+0] + lnib[d4+0]);
                    float o1 = tanh_fast(c1*inv*lniw[d4+1] + lnib[d4+1]);
                    float o2 = tanh_fast(c2*inv*lniw[d4+2] + lnib[d4+2]);
                    float o3 = tanh_fast(c3*inv*lniw[d4+3] + lnib[d4+3]);
                    hs[pp][d4+0] = o0; hs[pp][d4+1] = o1; hs[pp][d4+2] = o2; hs[pp][d4+3] = o3;
                    *(float4*)&hout[(size_t)n*DD + d4] = make_float4(o0,o1,o2,o3);
                } else {
                    float4 v = *(const float4*)&inb[(size_t)n*DD + d4];
                    float4 w4 = make_float4(1,1,1,1), b4 = make_float4(0,0,0,0);
                    if (gw) { w4 = *(const float4*)&gw[d4]; b4 = *(const float4*)&gb[d4]; }
                    hs[pp][d4+0] = (v.x-gm)*ginv*w4.x + b4.x;
                    hs[pp][d4+1] = (v.y-gm)*ginv*w4.y + b4.y;
                    hs[pp][d4+2] = (v.z-gm)*ginv*w4.z + b4.z;
                    hs[pp][d4+3] = (v.w-gm)*ginv*w4.w + b4.w;
                }
            }
        }
        __syncthreads();
        // ---- phase 2: xp + attn (8 threads per point)
        if (pt < np) {
            float xr[8] = {bi0.x,bi0.y,bi0.z,bi0.w,bi1.x,bi1.y,bi1.z,bi1.w};
            #pragma unroll
            for (int k = 0; k < DD; k++) {
                float hv = hs[pt][k];
                float4 wa = *(const float4*)&sWin[k*FF + fo];
                float4 wb = *(const float4*)&sWin[k*FF + fo + 4];
                xr[0] += hv*wa.x; xr[1] += hv*wa.y; xr[2] += hv*wa.z; xr[3] += hv*wa.w;
                xr[4] += hv*wb.x; xr[5] += hv*wb.y; xr[6] += hv*wb.z; xr[7] += hv*wb.w;
            }
            float pa[8];
            #pragma unroll
            for (int a = 0; a < 8; a++) {
                float4 wa = *(const float4*)&sScT[a*FF + fo];
                float4 wb = *(const float4*)&sScT[a*FF + fo + 4];
                pa[a] = xr[0]*wa.x + xr[1]*wa.y + xr[2]*wa.z + xr[3]*wa.w
                      + xr[4]*wb.x + xr[5]*wb.y + xr[6]*wb.z + xr[7]*wb.w;
            }
            #pragma unroll
            for (int msk = 1; msk < 8; msk <<= 1) {
                #pragma unroll
                for (int a = 0; a < 8; a++) pa[a] += __shfl_xor(pa[a], msk);
            }
            sattn[pt][q] = __expf(-fabsf(pa[q] + bscv));
            *(float4*)&sxp[pt][fo]   = make_float4(xr[0],xr[1],xr[2],xr[3]);
            *(float4*)&sxp[pt][fo+4] = make_float4(xr[4],xr[5],xr[6],xr[7]);
        }
        __syncthreads();
        // ---- phase 3: accumulate one (a,f) cell per thread
        for (int pp = 0; pp < np; pp++) {
            float w = sattn[pp][ca] * sxp[pp][cf];
            csum += w; cmax = fmaxf(cmax, w);
        }
    }
    psum[pb + t] = csum;
    pmax[pb + t] = cmax;
}

// ---------------------------------------------------------------- kC: graph-aligned; inline-B (unrolled 10-slot fold) -> out = tanh(gln@Weff + aggW) + stats
__global__ __launch_bounds__(512) void k_C(const float* __restrict__ inb,
                                           const float* __restrict__ stats,
                                           const float* __restrict__ gw,
                                           const float* __restrict__ gb,
                                           const int* __restrict__ offs,
                                           const float* __restrict__ psum,
                                           const float* __restrict__ pmax,
                                           const float* __restrict__ Wagg,   // W_out[j] + 96*DD
                                           const float* __restrict__ beff,
                                           const float* __restrict__ Weff,
                                           float* __restrict__ tbuf,
                                           float* __restrict__ statsO) {
    int g = blockIdx.x / SLOTS;
    int s = blockIdx.x - g*SLOTS;
    int gs = offs[g], cnt = offs[g+1] - gs;
    int start = s*CH;
    if (start >= cnt) return;                 // block-uniform early exit (no syncs yet)
    int end = (s == SLOTS-1) ? cnt : min(cnt, start + CH);

    __shared__ float hs[CH][36];
    __shared__ float sW[DD][36];
    __shared__ float agg[2*FF*AA];            // 1024
    __shared__ float red[16][DD];             // 512
    __shared__ float aggWs[DD];
    __shared__ float rs1[8], rs2[8];
    const int t = threadIdx.x;

    for (int k = t; k < DD*DD; k += 512) sW[k >> 5][k & 31] = Weff[k];

    // ---- inline B: fold all SLOTS partials (fully unrolled, independent loads)
    {
        float sum = 0.f, mx = -INFINITY;
        size_t pb = (size_t)g*SLOTS*512 + t;
        #pragma unroll
        for (int s2 = 0; s2 < SLOTS; s2++) {
            sum += psum[pb + s2*512];
            mx = fmaxf(mx, pmax[pb + s2*512]);
        }
        float mean = sum / (float)cnt;        // cnt > 0 for active blocks
        int a = t >> 6, f = t & 63;
        agg[a*2*FF + f]      = mean;
        agg[a*2*FF + FF + f] = mx;
    }
    __syncthreads();                          // agg + sW ready
    {
        int d = t & 31, grp = t >> 5;         // 16 groups x 64 k
        float acc = 0.f;
        #pragma unroll
        for (int k2 = 0; k2 < 64; k2++) {
            int k = grp*64 + k2;
            acc += agg[k] * Wagg[k*DD + d];
        }
        red[grp][d] = acc;
    }
    __syncthreads();
    if (t < DD) {
        float r = 0.f;
        #pragma unroll
        for (int qq = 0; qq < 16; qq++) r += red[qq][t];
        aggWs[t] = r + beff[t];
    }

    float gm = 0.f, ginv = 1.f;
    if (stats) {
        const float invM = 1.f/((float)NPTS*DD);
        gm = stats[0]*invM;
        float var = stats[1]*invM - gm*gm;
        ginv = 1.f/(sqrtf(fmaxf(var, 0.f)) + EPSV);
    }
    const int pt = t >> 3, d4 = (t & 7)*4;
    float s1 = 0.f, s2a = 0.f;
    for (int base = gs + start; base < gs + end; base += CH) {
        int np = min(CH, gs + end - base);
        __syncthreads();                      // aggWs ready (iter 0) / hs consumed (iter >0)
        if (pt < np) {                        // phase 1: load + gln into hs
            int n = base + pt;
            float4 v = *(const float4*)&inb[(size_t)n*DD + d4];
            float4 w4 = make_float4(1,1,1,1), b4 = make_float4(0,0,0,0);
            if (gw) { w4 = *(const float4*)&gw[d4]; b4 = *(const float4*)&gb[d4]; }
            hs[pt][d4+0] = (v.x-gm)*ginv*w4.x + b4.x;
            hs[pt][d4+1] = (v.y-gm)*ginv*w4.y + b4.y;
            hs[pt][d4+2] = (v.z-gm)*ginv*w4.z + b4.z;
            hs[pt][d4+3] = (v.w-gm)*ginv*w4.w + b4.w;
        }
        __syncthreads();
        if (pt < np) {                        // phase 2: matmul + tanh + store
            int n = base + pt;
            float4 a0 = *(const float4*)&aggWs[d4];
            float acc0 = a0.x, acc1 = a0.y, acc2 = a0.z, acc3 = a0.w;
            #pragma unroll
            for (int k = 0; k < DD; k++) {
                float hv = hs[pt][k];
                float4 w = *(const float4*)&sW[k][d4];
                acc0 += hv*w.x; acc1 += hv*w.y; acc2 += hv*w.z; acc3 += hv*w.w;
            }
            float4 o;
            o.x = tanh_fast(acc0); o.y = tanh_fast(acc1);
            o.z = tanh_fast(acc2); o.w = tanh_fast(acc3);
            *(float4*)&tbuf[(size_t)n*DD + d4] = o;
            s1  += (o.x + o.y) + (o.z + o.w);
            s2a += (o.x*o.x + o.y*o.y) + (o.z*o.z + o.w*o.w);
        }
    }
    // stats reduce -> one atomic pair per block
    #pragma unroll
    for (int o = 32; o > 0; o >>= 1) { s1 += __shfl_down(s1, o); s2a += __shfl_down(s2a, o); }
    int wid = t >> 6;
    if ((t & 63) == 0) { rs1[wid] = s1; rs2[wid] = s2a; }
    __syncthreads();
    if (t == 0) {
        float a1 = 0.f, a2 = 0.f;
        #pragma unroll
        for (int qq = 0; qq < 8; qq++) { a1 += rs1[qq]; a2 += rs2[qq]; }
        atomicAdd(&statsO[0], a1);
        atomicAdd(&statsO[1], a2);
    }
}

// ---------------------------------------------------------------- readout: segment mean of gln(tbuf) -> 3x (dense+ln+tanh) -> dot
__global__ __launch_bounds__(256) void k_read(const float* __restrict__ tbuf,
                                              const float* __restrict__ stats,
                                              const float* __restrict__ gw,
                                              const float* __restrict__ gb,
                                              const int* __restrict__ offs,
                                              const float* __restrict__ Wp,
                                              const float* __restrict__ bp,
                                              const float* __restrict__ lnw,
                                              const float* __restrict__ lnb,
                                              const float* __restrict__ Wpo,
                                              const float* __restrict__ bpo,
                                              float* __restrict__ out) {
    int g = blockIdx.x;
    int t = threadIdx.x;
    int d = t & 31, pl = t >> 5;   // 8 point-lanes x 32 dims
    int s0 = offs[g], e0 = offs[g+1];
    float acc = 0.f;
    for (int n = s0 + pl; n < e0; n += 8) acc += tbuf[(size_t)n*DD + d];
    __shared__ float red[8][DD];
    red[pl][d] = acc;
    __syncthreads();
    __shared__ float sv[DD];
    if (t < DD) {
        float r = 0.f;
        #pragma unroll
        for (int qq = 0; qq < 8; qq++) r += red[qq][t];
        const float invM = 1.f/((float)NPTS*DD);
        float m = stats[0]*invM;
        float var = stats[1]*invM - m*m;
        float inv = 1.f/(sqrtf(fmaxf(var, 0.f)) + EPSV);
        float cnt = (float)(e0 - s0);
        float mean = r / fmaxf(cnt, 1.f);
        sv[t] = (e0 > s0) ? (mean - m)*inv*gw[t] + gb[t] : 0.f;
    }
    __syncthreads();
    for (int j = 0; j < 3; j++) {
        float yv = 0.f;
        if (t < DD) {
            float y = bp[j*DD + t];
            #pragma unroll
            for (int i = 0; i < DD; i++) y += sv[i] * Wp[j*DD*DD + i*DD + t];
            float sum = y;
            #pragma unroll
            for (int o = 1; o < 32; o <<= 1) sum += __shfl_xor(sum, o);
            float m = sum * (1.f/DD);
            float c = y - m;
            float sq = c*c;
            #pragma unroll
            for (int o = 1; o < 32; o <<= 1) sq += __shfl_xor(sq, o);
            float var = sq * (1.f/DD);
            yv = tanh_fast(c / sqrtf(var + EPSV) * lnw[j*DD+t] + lnb[j*DD+t]);
        }
        __syncthreads();
        if (t < DD) sv[t] = yv;
        __syncthreads();
    }
    if (t < DD) {
        float p = sv[t] * Wpo[t];
        #pragma unroll
        for (int o = 1; o < 32; o <<= 1) p += __shfl_xor(p, o);
        if (t == 0) out[g] = p + bpo[0];
    }
}

extern "C" void kernel_launch(void* const* d_in, const int* in_sizes, int n_in,
                              void* d_out, int out_size, void* d_ws, size_t ws_size,
                              hipStream_t stream) {
    const float* x     = (const float*)d_in[0];
    const int*   batch = (const int*)  d_in[1];
    const float* Wi    = (const float*)d_in[2];
    const float* bi    = (const float*)d_in[3];
    const float* lni_w = (const float*)d_in[4];
    const float* lni_b = (const float*)d_in[5];
    const float* W_in  = (const float*)d_in[6];
    const float* b_in  = (const float*)d_in[7];
    const float* W_sc  = (const float*)d_in[8];
    const float* b_sc  = (const float*)d_in[9];
    const float* W_out = (const float*)d_in[10];
    const float* b_out = (const float*)d_in[11];
    const float* gln_w = (const float*)d_in[12];
    const float* gln_b = (const float*)d_in[13];
    const float* Wp    = (const float*)d_in[14];
    const float* bp    = (const float*)d_in[15];
    const float* lnp_w = (const float*)d_in[16];
    const float* lnp_b = (const float*)d_in[17];
    const float* Wpo   = (const float*)d_in[18];
    const float* bpo   = (const float*)d_in[19];
    float* out = (float*)d_out;

    float* ws    = (float*)d_ws;
    float* h     = ws;                                  // NPTS*32
    float* tbuf  = h + (size_t)NPTS*DD;                 // NPTS*32
    float* stats = tbuf + (size_t)NPTS*DD;              // 32
    float* Weff  = stats + 32;                          // 3*1024
    float* beff  = Weff + 3*DD*DD;                      // 96
    float* psum  = beff + 3*DD;                         // NG*SLOTS*512
    float* pmax  = psum + (size_t)NG*SLOTS*512;         // NG*SLOTS*512
    int*   offs  = (int*)(pmax + (size_t)NG*SLOTS*512); // NG+1

    k_setup<<<4, 256, 0, stream>>>(batch, W_in, b_in, W_out, b_out, offs, stats, Weff, beff);

    for (int L = 0; L < 9; ++L) {
        int j = L % 3;
        int pj = (L + 2) % 3;
        const float* inb = L ? tbuf : h;
        const float* st  = L ? stats + 2*(L-1) : nullptr;
        const float* pgw = L ? gln_w + pj*DD : nullptr;
        const float* pgb = L ? gln_b + pj*DD : nullptr;
        k_A<<<NG*SLOTS, 512, 0, stream>>>(
            x, Wi, bi, lni_w, lni_b,
            inb, st, pgw, pgb,
            W_in + (size_t)j*DD*FF, b_in + j*FF,
            W_sc + (size_t)j*FF*AA, b_sc + j*AA,
            offs, psum, pmax, h, (L == 0) ? 1 : 0);
        k_C<<<NG*SLOTS, 512, 0, stream>>>(
            inb, st, pgw, pgb, offs, psum, pmax,
            W_out + (size_t)j*HINC*DD + (size_t)96*DD, beff + j*DD,
            Weff + (size_t)j*DD*DD, tbuf, stats + 2*L);
    }
    k_read<<<NG, 256, 0, stream>>>(tbuf, stats + 16, gln_w + 2*DD, gln_b + 2*DD,
                                   offs, Wp, bp, lnp_w, lnp_b, Wpo, bpo, out);
}

// Round 13
// 371.709 us; speedup vs baseline: 5.6172x; 1.3075x over previous
//
#include <hip/hip_runtime.h>
#include <math.h>

#define NPTS 50000
#define NG   128
#define DD   32
#define FF   64
#define AA   8
#define HINC 1120   // DD + FF + 2*FF*AA
#define EPSV 1e-5f
#define CH   64

__device__ __forceinline__ float tanh_fast(float x) {
    float e = __expf(-2.f * fabsf(x));
    float r = __fdividef(1.f - e, 1.f + e);
    return copysignf(r, x);
}

// ---------------------------------------------------------------- setup: offs + stats zero + Weff/beff fold
__global__ __launch_bounds__(256) void k_setup(const int* __restrict__ batch,
                                               const float* __restrict__ W_in,
                                               const float* __restrict__ b_in,
                                               const float* __restrict__ W_out,
                                               const float* __restrict__ b_out,
                                               int* __restrict__ offs,
                                               float* __restrict__ stats,
                                               float* __restrict__ Weff,
                                               float* __restrict__ beff) {
    int t = threadIdx.x, bid = blockIdx.x;
    if (bid == 0) {
        if (t <= NG) {
            int lo = 0, hi = NPTS;
            while (lo < hi) { int mid = (lo+hi)>>1; if (batch[mid] < t) lo = mid+1; else hi = mid; }
            offs[t] = lo;
        }
        if (t < 32) stats[t] = 0.f;
    } else {
        int j = bid - 1;
        const float* W0 = W_out + (size_t)j*HINC*DD;   // rows 0..31
        const float* W1 = W0 + DD*DD;                  // rows 32..95
        const float* Wi = W_in + (size_t)j*DD*FF;
        for (int e = t; e < DD*DD; e += 256) {
            int i = e >> 5, d = e & 31;
            float s = W0[e];
            for (int f = 0; f < FF; f++) s += Wi[i*FF+f] * W1[f*DD+d];
            Weff[j*DD*DD + e] = s;
        }
        if (t < DD) {
            float s = b_out[j*DD + t];
            for (int f = 0; f < FF; f++) s += b_in[j*FF+f] * W1[f*DD+t];
            beff[j*DD + t] = s;
        }
    }
}

// ---------------------------------------------------------------- k_L: ONE kernel per layer, ONE block per graph.
// pass1: (embed|gln) -> xp -> attn -> register agg cells over all chunks
// fold:  agg -> aggWs = agg@Wagg + beff   (in LDS, zero redundancy)
// pass2: out = tanh(gln(in)@Weff + aggWs) -> tbuf, global stats
__global__ __launch_bounds__(512) void k_L(const float* __restrict__ x,
                                           const float* __restrict__ Wi,
                                           const float* __restrict__ bi,
                                           const float* __restrict__ lniw,
                                           const float* __restrict__ lnib,
                                           const float* __restrict__ inb,
                                           const float* __restrict__ stats,
                                           const float* __restrict__ gw,
                                           const float* __restrict__ gb,
                                           const float* __restrict__ Win,
                                           const float* __restrict__ bin,
                                           const float* __restrict__ Wsc,
                                           const float* __restrict__ bsc,
                                           const int* __restrict__ offs,
                                           float* __restrict__ hout,
                                           const float* __restrict__ Wagg,  // W_out[j] + 96*DD
                                           const float* __restrict__ beff,
                                           const float* __restrict__ Weff,
                                           float* __restrict__ tbuf,
                                           float* __restrict__ statsO,
                                           int isL0) {
    int g = blockIdx.x;
    int gs = offs[g], cnt = offs[g+1] - gs;
    const int t = threadIdx.x;
    if (cnt <= 0) return;                     // uniform, before any sync

    __shared__ float hs[CH][36];
    __shared__ float sxp[CH][68];             // padded: conflict-free
    __shared__ float sattn[CH][9];
    __shared__ float sWin[DD*FF];
    __shared__ float sScT[AA*FF];             // Wsc transposed [a][f]
    __shared__ float sW[DD][36];              // Weff padded
    __shared__ float agg[2*FF*AA];            // 1024
    __shared__ float red[16][DD];             // 512
    __shared__ float aggWs[DD];
    __shared__ float rs1[8], rs2[8];

    ((float4*)sWin)[t] = ((const float4*)Win)[t];              // 512 float4 == 2048 floats
    { int a = t >> 6, f = t & 63; sScT[t] = Wsc[f*AA + a]; }   // 512 == AA*FF
    for (int k = t; k < DD*DD; k += 512) sW[k >> 5][k & 31] = Weff[k];

    float gm = 0.f, ginv = 1.f;
    if (stats) {
        const float invM = 1.f/((float)NPTS*DD);
        gm = stats[0]*invM;
        float var = stats[1]*invM - gm*gm;
        ginv = 1.f/(sqrtf(fmaxf(var, 0.f)) + EPSV);
    }

    const int pt = t >> 3, q = t & 7;
    const int fo = q * 8;
    const int ca = t >> 6, cf = t & 63;
    const float bscv = bsc[q];
    const float4 bi0 = *(const float4*)&bin[fo];
    const float4 bi1 = *(const float4*)&bin[fo+4];
    float csum = 0.f, cmax = -INFINITY;

    // ================= pass 1: xp/attn -> register agg cells =================
    for (int base = gs; base < gs + cnt; base += CH) {
        int np = min(CH, gs + cnt - base);
        __syncthreads();                      // weights staged (iter 0) / LDS consumed (iter >0)
        // ---- phase 1: stage point rows into hs (embed for L0, gln-load otherwise)
        {
            int pp = t >> 3, d4 = (t & 7)*4;
            if (pp < np) {
                int n = base + pp;
                if (isL0) {
                    float x0 = x[n*3], x1 = x[n*3+1], x2 = x[n*3+2];
                    float tv0 = x0*Wi[d4+0] + x1*Wi[DD+d4+0] + x2*Wi[2*DD+d4+0] + bi[d4+0];
                    float tv1 = x0*Wi[d4+1] + x1*Wi[DD+d4+1] + x2*Wi[2*DD+d4+1] + bi[d4+1];
                    float tv2 = x0*Wi[d4+2] + x1*Wi[DD+d4+2] + x2*Wi[2*DD+d4+2] + bi[d4+2];
                    float tv3 = x0*Wi[d4+3] + x1*Wi[DD+d4+3] + x2*Wi[2*DD+d4+3] + bi[d4+3];
                    float sm = (tv0+tv1) + (tv2+tv3);
                    sm += __shfl_xor(sm, 1); sm += __shfl_xor(sm, 2); sm += __shfl_xor(sm, 4);
                    float mm = sm * (1.f/DD);
                    float c0 = tv0-mm, c1 = tv1-mm, c2 = tv2-mm, c3 = tv3-mm;
                    float qq = (c0*c0 + c1*c1) + (c2*c2 + c3*c3);
                    qq += __shfl_xor(qq, 1); qq += __shfl_xor(qq, 2); qq += __shfl_xor(qq, 4);
                    float inv = 1.f/sqrtf(qq*(1.f/DD) + EPSV);
                    float o0 = tanh_fast(c0*inv*lniw[d4+0] + lnib[d4+0]);
                    float o1 = tanh_fast(c1*inv*lniw[d4+1] + lnib[d4+1]);
                    float o2 = tanh_fast(c2*inv*lniw[d4+2] + lnib[d4+2]);
                    float o3 = tanh_fast(c3*inv*lniw[d4+3] + lnib[d4+3]);
                    hs[pp][d4+0] = o0; hs[pp][d4+1] = o1; hs[pp][d4+2] = o2; hs[pp][d4+3] = o3;
                    *(float4*)&hout[(size_t)n*DD + d4] = make_float4(o0,o1,o2,o3);
                } else {
                    float4 v = *(const float4*)&inb[(size_t)n*DD + d4];
                    float4 w4 = make_float4(1,1,1,1), b4 = make_float4(0,0,0,0);
                    if (gw) { w4 = *(const float4*)&gw[d4]; b4 = *(const float4*)&gb[d4]; }
                    hs[pp][d4+0] = (v.x-gm)*ginv*w4.x + b4.x;
                    hs[pp][d4+1] = (v.y-gm)*ginv*w4.y + b4.y;
                    hs[pp][d4+2] = (v.z-gm)*ginv*w4.z + b4.z;
                    hs[pp][d4+3] = (v.w-gm)*ginv*w4.w + b4.w;
                }
            }
        }
        __syncthreads();
        // ---- phase 2: xp + attn (8 threads per point)
        if (pt < np) {
            float xr[8] = {bi0.x,bi0.y,bi0.z,bi0.w,bi1.x,bi1.y,bi1.z,bi1.w};
            #pragma unroll
            for (int k = 0; k < DD; k++) {
                float hv = hs[pt][k];
                float4 wa = *(const float4*)&sWin[k*FF + fo];
                float4 wb = *(const float4*)&sWin[k*FF + fo + 4];
                xr[0] += hv*wa.x; xr[1] += hv*wa.y; xr[2] += hv*wa.z; xr[3] += hv*wa.w;
                xr[4] += hv*wb.x; xr[5] += hv*wb.y; xr[6] += hv*wb.z; xr[7] += hv*wb.w;
            }
            float pa[8];
            #pragma unroll
            for (int a = 0; a < 8; a++) {
                float4 wa = *(const float4*)&sScT[a*FF + fo];
                float4 wb = *(const float4*)&sScT[a*FF + fo + 4];
                pa[a] = xr[0]*wa.x + xr[1]*wa.y + xr[2]*wa.z + xr[3]*wa.w
                      + xr[4]*wb.x + xr[5]*wb.y + xr[6]*wb.z + xr[7]*wb.w;
            }
            #pragma unroll
            for (int msk = 1; msk < 8; msk <<= 1) {
                #pragma unroll
                for (int a = 0; a < 8; a++) pa[a] += __shfl_xor(pa[a], msk);
            }
            sattn[pt][q] = __expf(-fabsf(pa[q] + bscv));
            *(float4*)&sxp[pt][fo]   = make_float4(xr[0],xr[1],xr[2],xr[3]);
            *(float4*)&sxp[pt][fo+4] = make_float4(xr[4],xr[5],xr[6],xr[7]);
        }
        __syncthreads();
        // ---- phase 3: accumulate one (a,f) cell per thread (registers, all chunks)
        for (int pp = 0; pp < np; pp++) {
            float w = sattn[pp][ca] * sxp[pp][cf];
            csum += w; cmax = fmaxf(cmax, w);
        }
    }

    // ================= fold B: agg -> aggWs (zero redundancy) =================
    agg[ca*2*FF + cf]      = csum / (float)cnt;   // cnt > 0
    agg[ca*2*FF + FF + cf] = cmax;
    __syncthreads();
    {
        int d = t & 31, grp = t >> 5;             // 16 groups x 64 k
        float acc = 0.f;
        #pragma unroll
        for (int k2 = 0; k2 < 64; k2++) {
            int k = grp*64 + k2;
            acc += agg[k] * Wagg[k*DD + d];
        }
        red[grp][d] = acc;
    }
    __syncthreads();
    if (t < DD) {
        float r = 0.f;
        #pragma unroll
        for (int qq = 0; qq < 16; qq++) r += red[qq][t];
        aggWs[t] = r + beff[t];
    }

    // ================= pass 2: out = tanh(gln(in)@Weff + aggWs) =================
    float s1 = 0.f, s2a = 0.f;
    for (int base = gs; base < gs + cnt; base += CH) {
        int np = min(CH, gs + cnt - base);
        __syncthreads();                      // aggWs ready (iter 0) / hs consumed (iter >0)
        {
            int pp = t >> 3, d4 = (t & 7)*4;
            if (pp < np) {
                int n = base + pp;
                if (isL0) {                   // recompute embed (deterministic, no hout store)
                    float x0 = x[n*3], x1 = x[n*3+1], x2 = x[n*3+2];
                    float tv0 = x0*Wi[d4+0] + x1*Wi[DD+d4+0] + x2*Wi[2*DD+d4+0] + bi[d4+0];
                    float tv1 = x0*Wi[d4+1] + x1*Wi[DD+d4+1] + x2*Wi[2*DD+d4+1] + bi[d4+1];
                    float tv2 = x0*Wi[d4+2] + x1*Wi[DD+d4+2] + x2*Wi[2*DD+d4+2] + bi[d4+2];
                    float tv3 = x0*Wi[d4+3] + x1*Wi[DD+d4+3] + x2*Wi[2*DD+d4+3] + bi[d4+3];
                    float sm = (tv0+tv1) + (tv2+tv3);
                    sm += __shfl_xor(sm, 1); sm += __shfl_xor(sm, 2); sm += __shfl_xor(sm, 4);
                    float mm = sm * (1.f/DD);
                    float c0 = tv0-mm, c1 = tv1-mm, c2 = tv2-mm, c3 = tv3-mm;
                    float qq = (c0*c0 + c1*c1) + (c2*c2 + c3*c3);
                    qq += __shfl_xor(qq, 1); qq += __shfl_xor(qq, 2); qq += __shfl_xor(qq, 4);
                    float inv = 1.f/sqrtf(qq*(1.f/DD) + EPSV);
                    hs[pp][d4+0] = tanh_fast(c0*inv*lniw[d4+0] + lnib[d4+0]);
                    hs[pp][d4+1] = tanh_fast(c1*inv*lniw[d4+1] + lnib[d4+1]);
                    hs[pp][d4+2] = tanh_fast(c2*inv*lniw[d4+2] + lnib[d4+2]);
                    hs[pp][d4+3] = tanh_fast(c3*inv*lniw[d4+3] + lnib[d4+3]);
                } else {
                    float4 v = *(const float4*)&inb[(size_t)n*DD + d4];
                    float4 w4 = make_float4(1,1,1,1), b4 = make_float4(0,0,0,0);
                    if (gw) { w4 = *(const float4*)&gw[d4]; b4 = *(const float4*)&gb[d4]; }
                    hs[pp][d4+0] = (v.x-gm)*ginv*w4.x + b4.x;
                    hs[pp][d4+1] = (v.y-gm)*ginv*w4.y + b4.y;
                    hs[pp][d4+2] = (v.z-gm)*ginv*w4.z + b4.z;
                    hs[pp][d4+3] = (v.w-gm)*ginv*w4.w + b4.w;
                }
            }
        }
        __syncthreads();
        {
            int pp = t >> 3, d4 = (t & 7)*4;
            if (pp < np) {
                int n = base + pp;
                float4 a0 = *(const float4*)&aggWs[d4];
                float acc0 = a0.x, acc1 = a0.y, acc2 = a0.z, acc3 = a0.w;
                #pragma unroll
                for (int k = 0; k < DD; k++) {
                    float hv = hs[pp][k];
                    float4 w = *(const float4*)&sW[k][d4];
                    acc0 += hv*w.x; acc1 += hv*w.y; acc2 += hv*w.z; acc3 += hv*w.w;
                }
                float4 o;
                o.x = tanh_fast(acc0); o.y = tanh_fast(acc1);
                o.z = tanh_fast(acc2); o.w = tanh_fast(acc3);
                *(float4*)&tbuf[(size_t)n*DD + d4] = o;
                s1  += (o.x + o.y) + (o.z + o.w);
                s2a += (o.x*o.x + o.y*o.y) + (o.z*o.z + o.w*o.w);
            }
        }
    }
    // stats reduce -> one atomic pair per block
    #pragma unroll
    for (int o = 32; o > 0; o >>= 1) { s1 += __shfl_down(s1, o); s2a += __shfl_down(s2a, o); }
    int wid = t >> 6;
    if ((t & 63) == 0) { rs1[wid] = s1; rs2[wid] = s2a; }
    __syncthreads();
    if (t == 0) {
        float a1 = 0.f, a2 = 0.f;
        #pragma unroll
        for (int qq = 0; qq < 8; qq++) { a1 += rs1[qq]; a2 += rs2[qq]; }
        atomicAdd(&statsO[0], a1);
        atomicAdd(&statsO[1], a2);
    }
}

// ---------------------------------------------------------------- readout: segment mean of gln(tbuf) -> 3x (dense+ln+tanh) -> dot
__global__ __launch_bounds__(256) void k_read(const float* __restrict__ tbuf,
                                              const float* __restrict__ stats,
                                              const float* __restrict__ gw,
                                              const float* __restrict__ gb,
                                              const int* __restrict__ offs,
                                              const float* __restrict__ Wp,
                                              const float* __restrict__ bp,
                                              const float* __restrict__ lnw,
                                              const float* __restrict__ lnb,
                                              const float* __restrict__ Wpo,
                                              const float* __restrict__ bpo,
                                              float* __restrict__ out) {
    int g = blockIdx.x;
    int t = threadIdx.x;
    int d = t & 31, pl = t >> 5;   // 8 point-lanes x 32 dims
    int s0 = offs[g], e0 = offs[g+1];
    float acc = 0.f;
    for (int n = s0 + pl; n < e0; n += 8) acc += tbuf[(size_t)n*DD + d];
    __shared__ float red[8][DD];
    red[pl][d] = acc;
    __syncthreads();
    __shared__ float sv[DD];
    if (t < DD) {
        float r = 0.f;
        #pragma unroll
        for (int qq = 0; qq < 8; qq++) r += red[qq][t];
        const float invM = 1.f/((float)NPTS*DD);
        float m = stats[0]*invM;
        float var = stats[1]*invM - m*m;
        float inv = 1.f/(sqrtf(fmaxf(var, 0.f)) + EPSV);
        float cnt = (float)(e0 - s0);
        float mean = r / fmaxf(cnt, 1.f);
        sv[t] = (e0 > s0) ? (mean - m)*inv*gw[t] + gb[t] : 0.f;
    }
    __syncthreads();
    for (int j = 0; j < 3; j++) {
        float yv = 0.f;
        if (t < DD) {
            float y = bp[j*DD + t];
            #pragma unroll
            for (int i = 0; i < DD; i++) y += sv[i] * Wp[j*DD*DD + i*DD + t];
            float sum = y;
            #pragma unroll
            for (int o = 1; o < 32; o <<= 1) sum += __shfl_xor(sum, o);
            float m = sum * (1.f/DD);
            float c = y - m;
            float sq = c*c;
            #pragma unroll
            for (int o = 1; o < 32; o <<= 1) sq += __shfl_xor(sq, o);
            float var = sq * (1.f/DD);
            yv = tanh_fast(c / sqrtf(var + EPSV) * lnw[j*DD+t] + lnb[j*DD+t]);
        }
        __syncthreads();
        if (t < DD) sv[t] = yv;
        __syncthreads();
    }
    if (t < DD) {
        float p = sv[t] * Wpo[t];
        #pragma unroll
        for (int o = 1; o < 32; o <<= 1) p += __shfl_xor(p, o);
        if (t == 0) out[g] = p + bpo[0];
    }
}

extern "C" void kernel_launch(void* const* d_in, const int* in_sizes, int n_in,
                              void* d_out, int out_size, void* d_ws, size_t ws_size,
                              hipStream_t stream) {
    const float* x     = (const float*)d_in[0];
    const int*   batch = (const int*)  d_in[1];
    const float* Wi    = (const float*)d_in[2];
    const float* bi    = (const float*)d_in[3];
    const float* lni_w = (const float*)d_in[4];
    const float* lni_b = (const float*)d_in[5];
    const float* W_in  = (const float*)d_in[6];
    const float* b_in  = (const float*)d_in[7];
    const float* W_sc  = (const float*)d_in[8];
    const float* b_sc  = (const float*)d_in[9];
    const float* W_out = (const float*)d_in[10];
    const float* b_out = (const float*)d_in[11];
    const float* gln_w = (const float*)d_in[12];
    const float* gln_b = (const float*)d_in[13];
    const float* Wp    = (const float*)d_in[14];
    const float* bp    = (const float*)d_in[15];
    const float* lnp_w = (const float*)d_in[16];
    const float* lnp_b = (const float*)d_in[17];
    const float* Wpo   = (const float*)d_in[18];
    const float* bpo   = (const float*)d_in[19];
    float* out = (float*)d_out;

    float* ws    = (float*)d_ws;
    float* h     = ws;                                  // NPTS*32
    float* tbuf  = h + (size_t)NPTS*DD;                 // NPTS*32
    float* stats = tbuf + (size_t)NPTS*DD;              // 32
    float* Weff  = stats + 32;                          // 3*1024
    float* beff  = Weff + 3*DD*DD;                      // 96
    int*   offs  = (int*)(beff + 3*DD);                 // NG+1

    k_setup<<<4, 256, 0, stream>>>(batch, W_in, b_in, W_out, b_out, offs, stats, Weff, beff);

    for (int L = 0; L < 9; ++L) {
        int j = L % 3;
        int pj = (L + 2) % 3;
        const float* inb = L ? tbuf : h;
        const float* st  = L ? stats + 2*(L-1) : nullptr;
        const float* pgw = L ? gln_w + pj*DD : nullptr;
        const float* pgb = L ? gln_b + pj*DD : nullptr;
        k_L<<<NG, 512, 0, stream>>>(
            x, Wi, bi, lni_w, lni_b,
            inb, st, pgw, pgb,
            W_in + (size_t)j*DD*FF, b_in + j*FF,
            W_sc + (size_t)j*FF*AA, b_sc + j*AA,
            offs, h,
            W_out + (size_t)j*HINC*DD + (size_t)96*DD, beff + j*DD,
            Weff + (size_t)j*DD*DD, tbuf, stats + 2*L, (L == 0) ? 1 : 0);
    }
    k_read<<<NG, 256, 0, stream>>>(tbuf, stats + 16, gln_w + 2*DD, gln_b + 2*DD,
                                   offs, Wp, bp, lnp_w, lnp_b, Wpo, bpo, out);
}

// Round 14
// 352.487 us; speedup vs baseline: 5.9236x; 1.0545x over previous
//
#include <hip/hip_runtime.h>
#include <math.h>

#define NPTS 50000
#define NG   128
#define DD   32
#define FF   64
#define AA   8
#define HINC 1120   // DD + FF + 2*FF*AA
#define EPSV 1e-5f
#define CH   64

__device__ __forceinline__ float tanh_fast(float x) {
    float e = __expf(-2.f * fabsf(x));
    float r = __fdividef(1.f - e, 1.f + e);
    return copysignf(r, x);
}

// ---------------------------------------------------------------- setup: offs + stats zero + Weff/beff fold
__global__ __launch_bounds__(256) void k_setup(const int* __restrict__ batch,
                                               const float* __restrict__ W_in,
                                               const float* __restrict__ b_in,
                                               const float* __restrict__ W_out,
                                               const float* __restrict__ b_out,
                                               int* __restrict__ offs,
                                               float* __restrict__ stats,
                                               float* __restrict__ Weff,
                                               float* __restrict__ beff) {
    int t = threadIdx.x, bid = blockIdx.x;
    if (bid == 0) {
        if (t <= NG) {
            int lo = 0, hi = NPTS;
            while (lo < hi) { int mid = (lo+hi)>>1; if (batch[mid] < t) lo = mid+1; else hi = mid; }
            offs[t] = lo;
        }
        if (t < 32) stats[t] = 0.f;
    } else {
        int j = bid - 1;
        const float* W0 = W_out + (size_t)j*HINC*DD;   // rows 0..31
        const float* W1 = W0 + DD*DD;                  // rows 32..95
        const float* Wi = W_in + (size_t)j*DD*FF;
        for (int e = t; e < DD*DD; e += 256) {
            int i = e >> 5, d = e & 31;
            float s = W0[e];
            for (int f = 0; f < FF; f++) s += Wi[i*FF+f] * W1[f*DD+d];
            Weff[j*DD*DD + e] = s;
        }
        if (t < DD) {
            float s = b_out[j*DD + t];
            for (int f = 0; f < FF; f++) s += b_in[j*FF+f] * W1[f*DD+t];
            beff[j*DD + t] = s;
        }
    }
}

// ---------------------------------------------------------------- k_L: one kernel per layer, one block per graph.
// gln folded into staged weights; direct-global row reads (L>=1); reg prefetch.
__global__ __launch_bounds__(512) void k_L(const float* __restrict__ x,
                                           const float* __restrict__ Wi,
                                           const float* __restrict__ bi,
                                           const float* __restrict__ lniw,
                                           const float* __restrict__ lnib,
                                           const float* __restrict__ inb,
                                           const float* __restrict__ stats,
                                           const float* __restrict__ gw,
                                           const float* __restrict__ gb,
                                           const float* __restrict__ Win,
                                           const float* __restrict__ bin,
                                           const float* __restrict__ Wsc,
                                           const float* __restrict__ bsc,
                                           const int* __restrict__ offs,
                                           const float* __restrict__ Wagg,  // W_out[j] + 96*DD
                                           const float* __restrict__ beff,
                                           const float* __restrict__ Weff,
                                           float* __restrict__ tbuf,
                                           float* __restrict__ statsO,
                                           int isL0) {
    int g = blockIdx.x;
    int gs = offs[g], cnt = offs[g+1] - gs;
    const int t = threadIdx.x;
    if (cnt <= 0) return;                     // uniform, before any sync

    __shared__ float hs[CH][36];              // L0 embed staging only
    __shared__ float sxp[CH][68];             // padded: conflict-free
    __shared__ float sattn[CH][9];
    __shared__ float sWin[DD*FF];
    __shared__ float sScT[AA*FF];             // Wsc transposed [a][f]
    __shared__ float sW[DD][36];              // Weff padded (gln-scaled for L>=1)
    __shared__ float agg[2*FF*AA];            // 1024
    __shared__ float red[16][DD];             // 512
    __shared__ float aggWs[DD];
    __shared__ float sbin[FF];                // bin' (gln shift folded)
    __shared__ float shW[DD];                 // shift @ Weff
    __shared__ float rs1[8], rs2[8];

    ((float4*)sWin)[t] = ((const float4*)Win)[t];              // 512 float4 == 2048 floats
    { int a = t >> 6, f = t & 63; sScT[t] = Wsc[f*AA + a]; }   // 512 == AA*FF
    for (int k = t; k < DD*DD; k += 512) sW[k >> 5][k & 31] = Weff[k];

    float gm = 0.f, ginv = 1.f;
    if (!isL0) {
        const float invM = 1.f/((float)NPTS*DD);
        gm = stats[0]*invM;
        float var = stats[1]*invM - gm*gm;
        ginv = 1.f/(sqrtf(fmaxf(var, 0.f)) + EPSV);
    }
    __syncthreads();                          // raw weights staged
    if (!isL0) {
        // fold gln: bin' = bin + shift@Win ; shW = shift@Weff  (from RAW weights)
        if (t < FF) {
            float b = bin[t];
            for (int k = 0; k < DD; k++) {
                float sk = ginv * gw[k];
                float sh = gb[k] - gm * sk;
                b += sh * sWin[k*FF + t];
            }
            sbin[t] = b;
        } else if (t < FF + DD) {
            int d = t - FF;
            float r = 0.f;
            for (int k = 0; k < DD; k++) {
                float sk = ginv * gw[k];
                float sh = gb[k] - gm * sk;
                r += sh * sW[k][d];
            }
            shW[d] = r;
        }
        __syncthreads();                      // bin'/shW done reading raw weights
        for (int e = t; e < DD*FF; e += 512) sWin[e] *= ginv * gw[e >> 6];
        for (int e = t; e < DD*DD; e += 512) sW[e >> 5][e & 31] *= ginv * gw[e >> 5];
        __syncthreads();
    } else {
        if (t < FF) sbin[t] = bin[t];
        else if (t < FF + DD) shW[t - FF] = 0.f;
        __syncthreads();
    }

    const int pt = t >> 3, q = t & 7;
    const int fo = q * 8;
    const int ca = t >> 6, cf = t & 63;
    const float bscv = bsc[q];
    const float4 bi0 = *(const float4*)&sbin[fo];
    const float4 bi1 = *(const float4*)&sbin[fo+4];
    float csum = 0.f, cmax = -INFINITY;

    // ================= pass 1: xp/attn -> register agg cells =================
    if (isL0) {
        for (int base = gs; base < gs + cnt; base += CH) {
            int np = min(CH, gs + cnt - base);
            __syncthreads();
            {   // embed -> hs
                int pp = t >> 3, d4 = (t & 7)*4;
                if (pp < np) {
                    int n = base + pp;
                    float x0 = x[n*3], x1 = x[n*3+1], x2 = x[n*3+2];
                    float tv0 = x0*Wi[d4+0] + x1*Wi[DD+d4+0] + x2*Wi[2*DD+d4+0] + bi[d4+0];
                    float tv1 = x0*Wi[d4+1] + x1*Wi[DD+d4+1] + x2*Wi[2*DD+d4+1] + bi[d4+1];
                    float tv2 = x0*Wi[d4+2] + x1*Wi[DD+d4+2] + x2*Wi[2*DD+d4+2] + bi[d4+2];
                    float tv3 = x0*Wi[d4+3] + x1*Wi[DD+d4+3] + x2*Wi[2*DD+d4+3] + bi[d4+3];
                    float sm = (tv0+tv1) + (tv2+tv3);
                    sm += __shfl_xor(sm, 1); sm += __shfl_xor(sm, 2); sm += __shfl_xor(sm, 4);
                    float mm = sm * (1.f/DD);
                    float c0 = tv0-mm, c1 = tv1-mm, c2 = tv2-mm, c3 = tv3-mm;
                    float qq = (c0*c0 + c1*c1) + (c2*c2 + c3*c3);
                    qq += __shfl_xor(qq, 1); qq += __shfl_xor(qq, 2); qq += __shfl_xor(qq, 4);
                    float inv = 1.f/sqrtf(qq*(1.f/DD) + EPSV);
                    hs[pp][d4+0] = tanh_fast(c0*inv*lniw[d4+0] + lnib[d4+0]);
                    hs[pp][d4+1] = tanh_fast(c1*inv*lniw[d4+1] + lnib[d4+1]);
                    hs[pp][d4+2] = tanh_fast(c2*inv*lniw[d4+2] + lnib[d4+2]);
                    hs[pp][d4+3] = tanh_fast(c3*inv*lniw[d4+3] + lnib[d4+3]);
                }
            }
            __syncthreads();
            if (pt < np) {
                float xr[8] = {bi0.x,bi0.y,bi0.z,bi0.w,bi1.x,bi1.y,bi1.z,bi1.w};
                #pragma unroll
                for (int k = 0; k < DD; k++) {
                    float hv = hs[pt][k];
                    float4 wa = *(const float4*)&sWin[k*FF + fo];
                    float4 wb = *(const float4*)&sWin[k*FF + fo + 4];
                    xr[0] += hv*wa.x; xr[1] += hv*wa.y; xr[2] += hv*wa.z; xr[3] += hv*wa.w;
                    xr[4] += hv*wb.x; xr[5] += hv*wb.y; xr[6] += hv*wb.z; xr[7] += hv*wb.w;
                }
                float pa[8];
                #pragma unroll
                for (int a = 0; a < 8; a++) {
                    float4 wa = *(const float4*)&sScT[a*FF + fo];
                    float4 wb = *(const float4*)&sScT[a*FF + fo + 4];
                    pa[a] = xr[0]*wa.x + xr[1]*wa.y + xr[2]*wa.z + xr[3]*wa.w
                          + xr[4]*wb.x + xr[5]*wb.y + xr[6]*wb.z + xr[7]*wb.w;
                }
                #pragma unroll
                for (int msk = 1; msk < 8; msk <<= 1) {
                    #pragma unroll
                    for (int a = 0; a < 8; a++) pa[a] += __shfl_xor(pa[a], msk);
                }
                sattn[pt][q] = __expf(-fabsf(pa[q] + bscv));
                *(float4*)&sxp[pt][fo]   = make_float4(xr[0],xr[1],xr[2],xr[3]);
                *(float4*)&sxp[pt][fo+4] = make_float4(xr[4],xr[5],xr[6],xr[7]);
            }
            __syncthreads();
            for (int pp = 0; pp < np; pp++) {
                float w = sattn[pp][ca] * sxp[pp][cf];
                csum += w; cmax = fmaxf(cmax, w);
            }
        }
    } else {
        // direct-global rows, gln pre-folded, reg double-buffer prefetch
        float4 cur[8], nxt[8];
        {
            int n0 = gs + min(pt, cnt-1);
            const float4* r4 = (const float4*)(inb + (size_t)n0*DD);
            #pragma unroll
            for (int j = 0; j < 8; j++) cur[j] = r4[j];
        }
        for (int base = gs; base < gs + cnt; base += CH) {
            int np = min(CH, gs + cnt - base);
            {   // issue prefetch of next chunk's row (overlaps phase2+3)
                int nb = base + CH;
                int nclamp = (nb < gs + cnt) ? min(nb + pt, gs + cnt - 1) : gs;
                const float4* r4 = (const float4*)(inb + (size_t)nclamp*DD);
                #pragma unroll
                for (int j = 0; j < 8; j++) nxt[j] = r4[j];
            }
            __syncthreads();                  // sxp/sattn consumed by prior phase3
            if (pt < np) {
                float xr[8] = {bi0.x,bi0.y,bi0.z,bi0.w,bi1.x,bi1.y,bi1.z,bi1.w};
                #pragma unroll
                for (int k4 = 0; k4 < 8; k4++) {
                    float hv0 = cur[k4].x, hv1 = cur[k4].y, hv2 = cur[k4].z, hv3 = cur[k4].w;
                    int kb = k4*4;
                    float4 wa, wb;
                    wa = *(const float4*)&sWin[(kb+0)*FF + fo]; wb = *(const float4*)&sWin[(kb+0)*FF + fo + 4];
                    xr[0]+=hv0*wa.x; xr[1]+=hv0*wa.y; xr[2]+=hv0*wa.z; xr[3]+=hv0*wa.w;
                    xr[4]+=hv0*wb.x; xr[5]+=hv0*wb.y; xr[6]+=hv0*wb.z; xr[7]+=hv0*wb.w;
                    wa = *(const float4*)&sWin[(kb+1)*FF + fo]; wb = *(const float4*)&sWin[(kb+1)*FF + fo + 4];
                    xr[0]+=hv1*wa.x; xr[1]+=hv1*wa.y; xr[2]+=hv1*wa.z; xr[3]+=hv1*wa.w;
                    xr[4]+=hv1*wb.x; xr[5]+=hv1*wb.y; xr[6]+=hv1*wb.z; xr[7]+=hv1*wb.w;
                    wa = *(const float4*)&sWin[(kb+2)*FF + fo]; wb = *(const float4*)&sWin[(kb+2)*FF + fo + 4];
                    xr[0]+=hv2*wa.x; xr[1]+=hv2*wa.y; xr[2]+=hv2*wa.z; xr[3]+=hv2*wa.w;
                    xr[4]+=hv2*wb.x; xr[5]+=hv2*wb.y; xr[6]+=hv2*wb.z; xr[7]+=hv2*wb.w;
                    wa = *(const float4*)&sWin[(kb+3)*FF + fo]; wb = *(const float4*)&sWin[(kb+3)*FF + fo + 4];
                    xr[0]+=hv3*wa.x; xr[1]+=hv3*wa.y; xr[2]+=hv3*wa.z; xr[3]+=hv3*wa.w;
                    xr[4]+=hv3*wb.x; xr[5]+=hv3*wb.y; xr[6]+=hv3*wb.z; xr[7]+=hv3*wb.w;
                }
                float pa[8];
                #pragma unroll
                for (int a = 0; a < 8; a++) {
                    float4 wa = *(const float4*)&sScT[a*FF + fo];
                    float4 wb = *(const float4*)&sScT[a*FF + fo + 4];
                    pa[a] = xr[0]*wa.x + xr[1]*wa.y + xr[2]*wa.z + xr[3]*wa.w
                          + xr[4]*wb.x + xr[5]*wb.y + xr[6]*wb.z + xr[7]*wb.w;
                }
                #pragma unroll
                for (int msk = 1; msk < 8; msk <<= 1) {
                    #pragma unroll
                    for (int a = 0; a < 8; a++) pa[a] += __shfl_xor(pa[a], msk);
                }
                sattn[pt][q] = __expf(-fabsf(pa[q] + bscv));
                *(float4*)&sxp[pt][fo]   = make_float4(xr[0],xr[1],xr[2],xr[3]);
                *(float4*)&sxp[pt][fo+4] = make_float4(xr[4],xr[5],xr[6],xr[7]);
            }
            __syncthreads();
            for (int pp = 0; pp < np; pp++) {
                float w = sattn[pp][ca] * sxp[pp][cf];
                csum += w; cmax = fmaxf(cmax, w);
            }
            #pragma unroll
            for (int j = 0; j < 8; j++) cur[j] = nxt[j];
        }
    }

    // ================= fold B: agg -> aggWs (once per graph) =================
    agg[ca*2*FF + cf]      = csum / (float)cnt;   // cnt > 0
    agg[ca*2*FF + FF + cf] = cmax;
    __syncthreads();
    {
        int d = t & 31, grp = t >> 5;             // 16 groups x 64 k
        float acc = 0.f;
        #pragma unroll
        for (int k2 = 0; k2 < 64; k2++) {
            int k = grp*64 + k2;
            acc += agg[k] * Wagg[k*DD + d];
        }
        red[grp][d] = acc;
    }
    __syncthreads();
    if (t < DD) {
        float r = 0.f;
        #pragma unroll
        for (int qq = 0; qq < 16; qq++) r += red[qq][t];
        aggWs[t] = r + beff[t] + shW[t];
    }
    __syncthreads();                              // aggWs visible

    // ================= pass 2: out = tanh(row@sW + aggWs) =================
    float s1 = 0.f, s2a = 0.f;
    const int d4 = q * 4;
    if (isL0) {
        for (int base = gs; base < gs + cnt; base += CH) {
            int np = min(CH, gs + cnt - base);
            __syncthreads();
            {
                int pp = t >> 3;
                if (pp < np) {
                    int n = base + pp;
                    float x0 = x[n*3], x1 = x[n*3+1], x2 = x[n*3+2];
                    float tv0 = x0*Wi[d4+0] + x1*Wi[DD+d4+0] + x2*Wi[2*DD+d4+0] + bi[d4+0];
                    float tv1 = x0*Wi[d4+1] + x1*Wi[DD+d4+1] + x2*Wi[2*DD+d4+1] + bi[d4+1];
                    float tv2 = x0*Wi[d4+2] + x1*Wi[DD+d4+2] + x2*Wi[2*DD+d4+2] + bi[d4+2];
                    float tv3 = x0*Wi[d4+3] + x1*Wi[DD+d4+3] + x2*Wi[2*DD+d4+3] + bi[d4+3];
                    float sm = (tv0+tv1) + (tv2+tv3);
                    sm += __shfl_xor(sm, 1); sm += __shfl_xor(sm, 2); sm += __shfl_xor(sm, 4);
                    float mm = sm * (1.f/DD);
                    float c0 = tv0-mm, c1 = tv1-mm, c2 = tv2-mm, c3 = tv3-mm;
                    float qq = (c0*c0 + c1*c1) + (c2*c2 + c3*c3);
                    qq += __shfl_xor(qq, 1); qq += __shfl_xor(qq, 2); qq += __shfl_xor(qq, 4);
                    float inv = 1.f/sqrtf(qq*(1.f/DD) + EPSV);
                    hs[pp][d4+0] = tanh_fast(c0*inv*lniw[d4+0] + lnib[d4+0]);
                    hs[pp][d4+1] = tanh_fast(c1*inv*lniw[d4+1] + lnib[d4+1]);
                    hs[pp][d4+2] = tanh_fast(c2*inv*lniw[d4+2] + lnib[d4+2]);
                    hs[pp][d4+3] = tanh_fast(c3*inv*lniw[d4+3] + lnib[d4+3]);
                }
            }
            __syncthreads();
            {
                int pp = t >> 3;
                if (pp < np) {
                    int n = base + pp;
                    float4 a0 = *(const float4*)&aggWs[d4];
                    float acc0 = a0.x, acc1 = a0.y, acc2 = a0.z, acc3 = a0.w;
                    #pragma unroll
                    for (int k = 0; k < DD; k++) {
                        float hv = hs[pp][k];
                        float4 w = *(const float4*)&sW[k][d4];
                        acc0 += hv*w.x; acc1 += hv*w.y; acc2 += hv*w.z; acc3 += hv*w.w;
                    }
                    float4 o;
                    o.x = tanh_fast(acc0); o.y = tanh_fast(acc1);
                    o.z = tanh_fast(acc2); o.w = tanh_fast(acc3);
                    *(float4*)&tbuf[(size_t)n*DD + d4] = o;
                    s1  += (o.x + o.y) + (o.z + o.w);
                    s2a += (o.x*o.x + o.y*o.y) + (o.z*o.z + o.w*o.w);
                }
            }
        }
    } else {
        // barrier-free: each 8-thread group owns its rows (in-place safe by wave lockstep)
        float4 rcur[8], rnxt[8];
        if (pt < cnt) {
            {
                const float4* r4 = (const float4*)(inb + (size_t)(gs + pt)*DD);
                #pragma unroll
                for (int j = 0; j < 8; j++) rcur[j] = r4[j];
            }
            float4 a0 = *(const float4*)&aggWs[d4];
            for (int n = gs + pt; n < gs + cnt; n += CH) {
                int nn = n + CH;
                int nclamp = (nn < gs + cnt) ? nn : n;
                {
                    const float4* r4 = (const float4*)(inb + (size_t)nclamp*DD);
                    #pragma unroll
                    for (int j = 0; j < 8; j++) rnxt[j] = r4[j];
                }
                float acc0 = a0.x, acc1 = a0.y, acc2 = a0.z, acc3 = a0.w;
                #pragma unroll
                for (int k4 = 0; k4 < 8; k4++) {
                    float hv0 = rcur[k4].x, hv1 = rcur[k4].y, hv2 = rcur[k4].z, hv3 = rcur[k4].w;
                    int kb = k4*4;
                    float4 w;
                    w = *(const float4*)&sW[kb+0][d4];
                    acc0 += hv0*w.x; acc1 += hv0*w.y; acc2 += hv0*w.z; acc3 += hv0*w.w;
                    w = *(const float4*)&sW[kb+1][d4];
                    acc0 += hv1*w.x; acc1 += hv1*w.y; acc2 += hv1*w.z; acc3 += hv1*w.w;
                    w = *(const float4*)&sW[kb+2][d4];
                    acc0 += hv2*w.x; acc1 += hv2*w.y; acc2 += hv2*w.z; acc3 += hv2*w.w;
                    w = *(const float4*)&sW[kb+3][d4];
                    acc0 += hv3*w.x; acc1 += hv3*w.y; acc2 += hv3*w.z; acc3 += hv3*w.w;
                }
                float4 o;
                o.x = tanh_fast(acc0); o.y = tanh_fast(acc1);
                o.z = tanh_fast(acc2); o.w = tanh_fast(acc3);
                *(float4*)&tbuf[(size_t)n*DD + d4] = o;
                s1  += (o.x + o.y) + (o.z + o.w);
                s2a += (o.x*o.x + o.y*o.y) + (o.z*o.z + o.w*o.w);
                #pragma unroll
                for (int j = 0; j < 8; j++) rcur[j] = rnxt[j];
            }
        }
    }
    // stats reduce -> one atomic pair per block
    #pragma unroll
    for (int o = 32; o > 0; o >>= 1) { s1 += __shfl_down(s1, o); s2a += __shfl_down(s2a, o); }
    int wid = t >> 6;
    __syncthreads();
    if ((t & 63) == 0) { rs1[wid] = s1; rs2[wid] = s2a; }
    __syncthreads();
    if (t == 0) {
        float a1 = 0.f, a2 = 0.f;
        #pragma unroll
        for (int qq = 0; qq < 8; qq++) { a1 += rs1[qq]; a2 += rs2[qq]; }
        atomicAdd(&statsO[0], a1);
        atomicAdd(&statsO[1], a2);
    }
}

// ---------------------------------------------------------------- readout: segment mean of gln(tbuf) -> 3x (dense+ln+tanh) -> dot
__global__ __launch_bounds__(256) void k_read(const float* __restrict__ tbuf,
                                              const float* __restrict__ stats,
                                              const float* __restrict__ gw,
                                              const float* __restrict__ gb,
                                              const int* __restrict__ offs,
                                              const float* __restrict__ Wp,
                                              const float* __restrict__ bp,
                                              const float* __restrict__ lnw,
                                              const float* __restrict__ lnb,
                                              const float* __restrict__ Wpo,
                                              const float* __restrict__ bpo,
                                              float* __restrict__ out) {
    int g = blockIdx.x;
    int t = threadIdx.x;
    int d = t & 31, pl = t >> 5;   // 8 point-lanes x 32 dims
    int s0 = offs[g], e0 = offs[g+1];
    float acc = 0.f;
    for (int n = s0 + pl; n < e0; n += 8) acc += tbuf[(size_t)n*DD + d];
    __shared__ float red[8][DD];
    red[pl][d] = acc;
    __syncthreads();
    __shared__ float sv[DD];
    if (t < DD) {
        float r = 0.f;
        #pragma unroll
        for (int qq = 0; qq < 8; qq++) r += red[qq][t];
        const float invM = 1.f/((float)NPTS*DD);
        float m = stats[0]*invM;
        float var = stats[1]*invM - m*m;
        float inv = 1.f/(sqrtf(fmaxf(var, 0.f)) + EPSV);
        float cnt = (float)(e0 - s0);
        float mean = r / fmaxf(cnt, 1.f);
        sv[t] = (e0 > s0) ? (mean - m)*inv*gw[t] + gb[t] : 0.f;
    }
    __syncthreads();
    for (int j = 0; j < 3; j++) {
        float yv = 0.f;
        if (t < DD) {
            float y = bp[j*DD + t];
            #pragma unroll
            for (int i = 0; i < DD; i++) y += sv[i] * Wp[j*DD*DD + i*DD + t];
            float sum = y;
            #pragma unroll
            for (int o = 1; o < 32; o <<= 1) sum += __shfl_xor(sum, o);
            float m = sum * (1.f/DD);
            float c = y - m;
            float sq = c*c;
            #pragma unroll
            for (int o = 1; o < 32; o <<= 1) sq += __shfl_xor(sq, o);
            float var = sq * (1.f/DD);
            yv = tanh_fast(c / sqrtf(var + EPSV) * lnw[j*DD+t] + lnb[j*DD+t]);
        }
        __syncthreads();
        if (t < DD) sv[t] = yv;
        __syncthreads();
    }
    if (t < DD) {
        float p = sv[t] * Wpo[t];
        #pragma unroll
        for (int o = 1; o < 32; o <<= 1) p += __shfl_xor(p, o);
        if (t == 0) out[g] = p + bpo[0];
    }
}

extern "C" void kernel_launch(void* const* d_in, const int* in_sizes, int n_in,
                              void* d_out, int out_size, void* d_ws, size_t ws_size,
                              hipStream_t stream) {
    const float* x     = (const float*)d_in[0];
    const int*   batch = (const int*)  d_in[1];
    const float* Wi    = (const float*)d_in[2];
    const float* bi    = (const float*)d_in[3];
    const float* lni_w = (const float*)d_in[4];
    const float* lni_b = (const float*)d_in[5];
    const float* W_in  = (const float*)d_in[6];
    const float* b_in  = (const float*)d_in[7];
    const float* W_sc  = (const float*)d_in[8];
    const float* b_sc  = (const float*)d_in[9];
    const float* W_out = (const float*)d_in[10];
    const float* b_out = (const float*)d_in[11];
    const float* gln_w = (const float*)d_in[12];
    const float* gln_b = (const float*)d_in[13];
    const float* Wp    = (const float*)d_in[14];
    const float* bp    = (const float*)d_in[15];
    const float* lnp_w = (const float*)d_in[16];
    const float* lnp_b = (const float*)d_in[17];
    const float* Wpo   = (const float*)d_in[18];
    const float* bpo   = (const float*)d_in[19];
    float* out = (float*)d_out;

    float* ws    = (float*)d_ws;
    float* tbuf  = ws;                                  // NPTS*32
    float* stats = tbuf + (size_t)NPTS*DD;              // 32
    float* Weff  = stats + 32;                          // 3*1024
    float* beff  = Weff + 3*DD*DD;                      // 96
    int*   offs  = (int*)(beff + 3*DD);                 // NG+1

    k_setup<<<4, 256, 0, stream>>>(batch, W_in, b_in, W_out, b_out, offs, stats, Weff, beff);

    for (int L = 0; L < 9; ++L) {
        int j = L % 3;
        int pj = (L + 2) % 3;
        const float* st  = L ? stats + 2*(L-1) : nullptr;
        const float* pgw = L ? gln_w + pj*DD : nullptr;
        const float* pgb = L ? gln_b + pj*DD : nullptr;
        k_L<<<NG, 512, 0, stream>>>(
            x, Wi, bi, lni_w, lni_b,
            tbuf, st, pgw, pgb,
            W_in + (size_t)j*DD*FF, b_in + j*FF,
            W_sc + (size_t)j*FF*AA, b_sc + j*AA,
            offs,
            W_out + (size_t)j*HINC*DD + (size_t)96*DD, beff + j*DD,
            Weff + (size_t)j*DD*DD, tbuf, stats + 2*L, (L == 0) ? 1 : 0);
    }
    k_read<<<NG, 256, 0, stream>>>(tbuf, stats + 16, gln_w + 2*DD, gln_b + 2*DD,
                                   offs, Wp, bp, lnp_w, lnp_b, Wpo, bpo, out);
}